// Round 3
// baseline (160.013 us; speedup 1.0000x reference)
//
#include <hip/hip_runtime.h>
#include <hip/hip_bf16.h>
#include <math.h>

#define NN 768
#define DD 64
#define SS 32
#define PP 4

// mu = linspace(0,12,32) -> step 12/31 ; sigma = 12/32
#define MU_STEP   (12.0f / 31.0f)
#define INV2SIG2  3.55555555555f
// exp(-t^2*INV2SIG2) == exp2(t^2 * NEG2C)
#define NEG2C     (-INV2SIG2 * 1.4426950408889634f)

// ---------------------------------------------------------------------------
// Kernel 1: T[x][j*32+s] = sum_i hid[x][i] * W[i][j][s]   (192 blocks)
// Blocks 0..11 additionally transpose hid (768x64) -> hidT (64x768).
// Also zeroes the last-block counter for k2's fused final reduction.
// ---------------------------------------------------------------------------
__global__ __launch_bounds__(256) void k1_T(const float* __restrict__ hid,
                                            const float* __restrict__ W,
                                            float* __restrict__ T,
                                            float* __restrict__ hidT,
                                            unsigned* __restrict__ ctr) {
    if (blockIdx.x == 0 && threadIdx.x == 0) *ctr = 0u;

    const int b   = blockIdx.x;
    const int cb  = b & 3;        // c0 = cb*512
    const int xb  = b >> 2;       // x0 = xb*16
    const int c0  = cb * 512;
    const int x0  = xb * 16;
    const int tid = threadIdx.x;
    const int ct  = tid & 63;     // 0..63 -> 8 c's each
    const int xt  = tid >> 6;     // 0..3  -> 4 x's each

    __shared__ float hs[16 * 64];
    __shared__ float tile[64][65];   // transpose staging (blocks < 12)

    {
        const float4 v = *reinterpret_cast<const float4*>(&hid[(size_t)x0 * 64 + tid * 4]);
        *reinterpret_cast<float4*>(&hs[tid * 4]) = v;
    }
    __syncthreads();

    float acc[4][8];
#pragma unroll
    for (int m = 0; m < 4; ++m)
#pragma unroll
        for (int u = 0; u < 8; ++u) acc[m][u] = 0.0f;

    const int cbase = c0 + ct * 8;
#pragma unroll 4
    for (int i = 0; i < 64; ++i) {
        const float4 w0 = *reinterpret_cast<const float4*>(&W[(size_t)i * 2048 + cbase]);
        const float4 w1 = *reinterpret_cast<const float4*>(&W[(size_t)i * 2048 + cbase + 4]);
#pragma unroll
        for (int m = 0; m < 4; ++m) {
            const float hm = hs[(xt * 4 + m) * 64 + i];
            acc[m][0] += hm * w0.x; acc[m][1] += hm * w0.y;
            acc[m][2] += hm * w0.z; acc[m][3] += hm * w0.w;
            acc[m][4] += hm * w1.x; acc[m][5] += hm * w1.y;
            acc[m][6] += hm * w1.z; acc[m][7] += hm * w1.w;
        }
    }

#pragma unroll
    for (int m = 0; m < 4; ++m) {
        const int x = x0 + xt * 4 + m;
        float4 o0, o1;
        o0.x = acc[m][0]; o0.y = acc[m][1]; o0.z = acc[m][2]; o0.w = acc[m][3];
        o1.x = acc[m][4]; o1.y = acc[m][5]; o1.z = acc[m][6]; o1.w = acc[m][7];
        *reinterpret_cast<float4*>(&T[(size_t)x * 2048 + cbase])     = o0;
        *reinterpret_cast<float4*>(&T[(size_t)x * 2048 + cbase + 4]) = o1;
    }

    // ---- transpose duty for blocks 0..11 (uniform branch per block) ----
    if (b < 12) {
        const int y0t = b * 64;
        const int yy  = tid >> 2;      // 0..63
        const int seg = tid & 3;       // 0..3 (16 floats each)
#pragma unroll
        for (int c = 0; c < 4; ++c) {
            const float4 v = *reinterpret_cast<const float4*>(
                &hid[(size_t)(y0t + yy) * 64 + seg * 16 + c * 4]);
            tile[yy][seg * 16 + c * 4 + 0] = v.x;
            tile[yy][seg * 16 + c * 4 + 1] = v.y;
            tile[yy][seg * 16 + c * 4 + 2] = v.z;
            tile[yy][seg * 16 + c * 4 + 3] = v.w;
        }
        __syncthreads();
        const int ii = tid >> 2;       // 0..63 (i index)
#pragma unroll
        for (int c = 0; c < 4; ++c) {
            float4 o;
            o.x = tile[seg * 16 + c * 4 + 0][ii];
            o.y = tile[seg * 16 + c * 4 + 1][ii];
            o.z = tile[seg * 16 + c * 4 + 2][ii];
            o.w = tile[seg * 16 + c * 4 + 3][ii];
            *reinterpret_cast<float4*>(&hidT[(size_t)ii * 768 + y0t + seg * 16 + c * 4]) = o;
        }
    }
}

// ---------------------------------------------------------------------------
// Kernel 2: fused inter-GEMM + rbf epilogue + reductions.
// One block per x (768 blocks), 256 threads = 4 waves, 2 blocks/CU (64KB LDS).
//   wave ts owns s-block [ts*8, ts*8+8) ; lane ty owns 4 contiguous y rows
// T delivered via wave-uniform scalar loads (SGPR operand into v_fmac);
// h chunk (256 rows, transposed) staged via global_load_lds width-16;
// inner-loop LDS traffic = one conflict-free ds_read_b128 per j.
// ---------------------------------------------------------------------------
__global__ __launch_bounds__(256, 2) void k2_main(const float* __restrict__ hidT,
                                                  const float* __restrict__ coords,
                                                  const float* __restrict__ b_rbf,
                                                  const float* __restrict__ Tg,
                                                  float* __restrict__ partials,
                                                  unsigned* __restrict__ ctr,
                                                  const float* __restrict__ weight,
                                                  const float* __restrict__ bias_,
                                                  float* __restrict__ out) {
    const int x   = blockIdx.x;
    const int tid = threadIdx.x;
    const int ty  = tid & 63;
    const int wv  = __builtin_amdgcn_readfirstlane(tid >> 6);  // uniform wave id

    __shared__ float h_t[64 * 256];   // 65536 B exactly

    // wave-uniform T slice pointer -> scalar loads
    const float* Tw = Tg + (size_t)x * 2048 + wv * 8;

    // per-wave rbf constants for s = wv*8+u :
    //   arg = NEG2C*d^2 + A_u*d + B_u   (expanded (d-mu)^2*NEG2C)
    float A_u[8], B_u[8], b_reg[8];
#pragma unroll
    for (int u = 0; u < 8; ++u) {
        const float mu = (float)(wv * 8 + u) * MU_STEP;
        A_u[u] = -2.0f * NEG2C * mu;
        B_u[u] = NEG2C * mu * mu;
        b_reg[u] = b_rbf[wv * 8 + u];
    }
    float cx[PP][3];
#pragma unroll
    for (int p = 0; p < PP; ++p)
#pragma unroll
        for (int c = 0; c < 3; ++c)
            cx[p][c] = coords[(size_t)p * NN * 3 + (size_t)x * 3 + c];

    float e[PP] = {0.0f, 0.0f, 0.0f, 0.0f};

    for (int ch = 0; ch < 3; ++ch) {
        const int y0 = ch * 256;
        __syncthreads();   // previous chunk's readers done before DMA overwrite
        {
            // stage h_t[j][0..255] = hidT[j][y0..y0+255]; wave wv does rows j=k*4+wv
            const float* src = hidT + (size_t)y0 + (size_t)ty * 4;
#pragma unroll
            for (int k = 0; k < 16; ++k) {
                const int j = k * 4 + wv;
                __builtin_amdgcn_global_load_lds(
                    (const __attribute__((address_space(1))) void*)(const void*)(src + (size_t)j * 768),
                    (__attribute__((address_space(3))) void*)(void*)(&h_t[j * 256]),
                    16, 0, 0);
            }
        }
        __syncthreads();   // drains vmcnt -> DMA complete

        float acc[4][8];
#pragma unroll
        for (int i = 0; i < 4; ++i)
#pragma unroll
            for (int u = 0; u < 8; ++u) acc[i][u] = 0.0f;

#pragma unroll 4
        for (int j = 0; j < 64; ++j) {
            const float4 h4 = *reinterpret_cast<const float4*>(&h_t[j * 256 + ty * 4]);
            const float4 t0 = *reinterpret_cast<const float4*>(&Tw[j * 32]);      // uniform -> s_load
            const float4 t1 = *reinterpret_cast<const float4*>(&Tw[j * 32 + 4]);  // uniform -> s_load
            acc[0][0] += h4.x * t0.x; acc[0][1] += h4.x * t0.y; acc[0][2] += h4.x * t0.z; acc[0][3] += h4.x * t0.w;
            acc[0][4] += h4.x * t1.x; acc[0][5] += h4.x * t1.y; acc[0][6] += h4.x * t1.z; acc[0][7] += h4.x * t1.w;
            acc[1][0] += h4.y * t0.x; acc[1][1] += h4.y * t0.y; acc[1][2] += h4.y * t0.z; acc[1][3] += h4.y * t0.w;
            acc[1][4] += h4.y * t1.x; acc[1][5] += h4.y * t1.y; acc[1][6] += h4.y * t1.z; acc[1][7] += h4.y * t1.w;
            acc[2][0] += h4.z * t0.x; acc[2][1] += h4.z * t0.y; acc[2][2] += h4.z * t0.z; acc[2][3] += h4.z * t0.w;
            acc[2][4] += h4.z * t1.x; acc[2][5] += h4.z * t1.y; acc[2][6] += h4.z * t1.z; acc[2][7] += h4.z * t1.w;
            acc[3][0] += h4.w * t0.x; acc[3][1] += h4.w * t0.y; acc[3][2] += h4.w * t0.z; acc[3][3] += h4.w * t0.w;
            acc[3][4] += h4.w * t1.x; acc[3][5] += h4.w * t1.y; acc[3][6] += h4.w * t1.z; acc[3][7] += h4.w * t1.w;
        }

        float ab[4][8];
#pragma unroll
        for (int i = 0; i < 4; ++i)
#pragma unroll
            for (int u = 0; u < 8; ++u) ab[i][u] = acc[i][u] + b_reg[u];

#pragma unroll
        for (int i = 0; i < 4; ++i) {
            const int y = y0 + ty * 4 + i;
            if (y == x) continue;  // diagonal mask
#pragma unroll
            for (int p = 0; p < PP; ++p) {
                const float dx = cx[p][0] - coords[(size_t)p * NN * 3 + (size_t)y * 3 + 0];
                const float dy = cx[p][1] - coords[(size_t)p * NN * 3 + (size_t)y * 3 + 1];
                const float dz = cx[p][2] - coords[(size_t)p * NN * 3 + (size_t)y * 3 + 2];
                const float d2 = fmaf(dx, dx, fmaf(dy, dy, fmaf(dz, dz, 1e-12f)));
                const float d  = sqrtf(d2);
                const float cd2 = d2 * NEG2C;
                float ep = 0.0f;
#pragma unroll
                for (int u = 0; u < 8; ++u) {
                    const float arg = fmaf(A_u[u], d, cd2 + B_u[u]);
                    ep = fmaf(ab[i][u], __builtin_exp2f(arg), ep);
                }
                e[p] += ep;
            }
        }
    }

    // --- deterministic reduction: wave butterfly, then 4 partials in LDS ---
#pragma unroll
    for (int off = 1; off < 64; off <<= 1)
#pragma unroll
        for (int p = 0; p < PP; ++p) e[p] += __shfl_xor(e[p], off, 64);

    __syncthreads();                 // all waves done with h_t; reuse as scratch
    if (ty == 0) {
#pragma unroll
        for (int p = 0; p < PP; ++p) h_t[wv * 4 + p] = e[p];
    }
    __syncthreads();
    if (tid < 4) {
        const float s = h_t[0 * 4 + tid] + h_t[1 * 4 + tid] +
                        h_t[2 * 4 + tid] + h_t[3 * 4 + tid];
        partials[(size_t)x * 4 + tid] = s;
    }

    // --- fused final reduction: last block sums all partials ---
    __threadfence();
    __syncthreads();
    unsigned* flag = reinterpret_cast<unsigned*>(&h_t[16]);
    if (tid == 0) {
        const unsigned old = atomicAdd(ctr, 1u);
        *flag = (old == NN - 1) ? 1u : 0u;
    }
    __syncthreads();
    if (*flag) {
        __threadfence();  // acquire: make all partials visible
        const int p    = tid >> 6;
        const int lane = tid & 63;
        float s = 0.0f;
#pragma unroll
        for (int k = 0; k < 12; ++k)
            s += partials[(size_t)(lane * 12 + k) * 4 + p];
#pragma unroll
        for (int off = 1; off < 64; off <<= 1) s += __shfl_xor(s, off, 64);
        if (lane == 0)
            out[p] = s * (1.0f / 18874368.0f) * weight[0] + bias_[0];
    }
}

// ---------------------------------------------------------------------------
// Fallback path (ws too small): self-contained kernel (R2-proven structure)
// ---------------------------------------------------------------------------
__global__ __launch_bounds__(256, 4) void k2_fb(const float* __restrict__ hid,
                                                const float* __restrict__ coords,
                                                const float* __restrict__ W,
                                                const float* __restrict__ b_rbf,
                                                float* __restrict__ partials) {
    const int x   = blockIdx.x;
    const int tid = threadIdx.x;
    const int ty  = tid & 63;
    const int ts  = tid >> 6;

    __shared__ float pool[2048 + 64 * 128];
    float* T_l = pool;
    float* h_t = pool + 2048;

    {
        float a0[4] = {0, 0, 0, 0}, a1[4] = {0, 0, 0, 0};
        for (int i = 0; i < 64; ++i) {
            const float hv = hid[(size_t)x * 64 + i];
            const float4 w0 = *reinterpret_cast<const float4*>(&W[(size_t)i * 2048 + tid * 4]);
            const float4 w1 = *reinterpret_cast<const float4*>(&W[(size_t)i * 2048 + 1024 + tid * 4]);
            a0[0] += hv * w0.x; a0[1] += hv * w0.y; a0[2] += hv * w0.z; a0[3] += hv * w0.w;
            a1[0] += hv * w1.x; a1[1] += hv * w1.y; a1[2] += hv * w1.z; a1[3] += hv * w1.w;
        }
        T_l[tid * 4 + 0] = a0[0]; T_l[tid * 4 + 1] = a0[1];
        T_l[tid * 4 + 2] = a0[2]; T_l[tid * 4 + 3] = a0[3];
        T_l[1024 + tid * 4 + 0] = a1[0]; T_l[1024 + tid * 4 + 1] = a1[1];
        T_l[1024 + tid * 4 + 2] = a1[2]; T_l[1024 + tid * 4 + 3] = a1[3];
    }

    float mu_reg[8], b_reg[8];
#pragma unroll
    for (int u = 0; u < 8; ++u) {
        const int s = ts * 8 + u;
        mu_reg[u] = (float)s * MU_STEP;
        b_reg[u]  = b_rbf[s];
    }
    float cx[PP][3];
#pragma unroll
    for (int p = 0; p < PP; ++p)
#pragma unroll
        for (int c = 0; c < 3; ++c)
            cx[p][c] = coords[(size_t)p * NN * 3 + (size_t)x * 3 + c];

    float e[PP] = {0.0f, 0.0f, 0.0f, 0.0f};
    const int srow = tid >> 1;
    const int r0   = (tid & 1) * 8;
    const int hoff = ty * 2;
    const int toff = ts * 8;

    for (int ch = 0; ch < 6; ++ch) {
        const int y0 = ch * 128;
        __syncthreads();
        {
            const int y = y0 + srow;
#pragma unroll
            for (int r = 0; r < 8; ++r) {
                const float4 v = *reinterpret_cast<const float4*>(
                    &hid[(size_t)y * 64 + (r0 + r) * 4]);
                const int j = (r0 + r) * 4;
                h_t[(j + 0) * 128 + srow] = v.x;
                h_t[(j + 1) * 128 + srow] = v.y;
                h_t[(j + 2) * 128 + srow] = v.z;
                h_t[(j + 3) * 128 + srow] = v.w;
            }
        }
        __syncthreads();

        float acc[2][8];
#pragma unroll
        for (int i = 0; i < 2; ++i)
#pragma unroll
            for (int u = 0; u < 8; ++u) acc[i][u] = 0.0f;

#pragma unroll 4
        for (int j = 0; j < 64; ++j) {
            const float h0 = h_t[j * 128 + hoff];
            const float h1 = h_t[j * 128 + hoff + 1];
            const float4 t0 = *reinterpret_cast<const float4*>(&T_l[j * 32 + toff]);
            const float4 t1 = *reinterpret_cast<const float4*>(&T_l[j * 32 + toff + 4]);
            acc[0][0] += h0 * t0.x; acc[0][1] += h0 * t0.y; acc[0][2] += h0 * t0.z; acc[0][3] += h0 * t0.w;
            acc[0][4] += h0 * t1.x; acc[0][5] += h0 * t1.y; acc[0][6] += h0 * t1.z; acc[0][7] += h0 * t1.w;
            acc[1][0] += h1 * t0.x; acc[1][1] += h1 * t0.y; acc[1][2] += h1 * t0.z; acc[1][3] += h1 * t0.w;
            acc[1][4] += h1 * t1.x; acc[1][5] += h1 * t1.y; acc[1][6] += h1 * t1.z; acc[1][7] += h1 * t1.w;
        }

        float ab[2][8];
#pragma unroll
        for (int i = 0; i < 2; ++i)
#pragma unroll
            for (int u = 0; u < 8; ++u) ab[i][u] = acc[i][u] + b_reg[u];

#pragma unroll
        for (int i = 0; i < 2; ++i) {
            const int y = y0 + hoff + i;
            if (y == x) continue;
#pragma unroll
            for (int p = 0; p < PP; ++p) {
                const float dx = cx[p][0] - coords[(size_t)p * NN * 3 + (size_t)y * 3 + 0];
                const float dy = cx[p][1] - coords[(size_t)p * NN * 3 + (size_t)y * 3 + 1];
                const float dz = cx[p][2] - coords[(size_t)p * NN * 3 + (size_t)y * 3 + 2];
                const float d  = sqrtf(dx * dx + dy * dy + dz * dz + 1e-12f);
                float ep = 0.0f;
#pragma unroll
                for (int u = 0; u < 8; ++u) {
                    const float t = d - mu_reg[u];
                    const float w = __builtin_exp2f(t * t * NEG2C);
                    ep = fmaf(ab[i][u], w, ep);
                }
                e[p] += ep;
            }
        }
    }

#pragma unroll
    for (int off = 1; off < 64; off <<= 1)
#pragma unroll
        for (int p = 0; p < PP; ++p) e[p] += __shfl_xor(e[p], off, 64);

    __syncthreads();
    if (ty == 0) {
#pragma unroll
        for (int p = 0; p < PP; ++p) pool[ts * 4 + p] = e[p];
    }
    __syncthreads();
    if (tid < 4) {
        const float s = pool[0 * 4 + tid] + pool[1 * 4 + tid] +
                        pool[2 * 4 + tid] + pool[3 * 4 + tid];
        partials[(size_t)x * 4 + tid] = s;
    }
}

__global__ __launch_bounds__(256) void k3_final(const float* __restrict__ partials,
                                                const float* __restrict__ weight,
                                                const float* __restrict__ bias_,
                                                float* __restrict__ out) {
    const int p    = threadIdx.x >> 6;
    const int lane = threadIdx.x & 63;
    float s = 0.0f;
#pragma unroll
    for (int k = 0; k < 12; ++k) s += partials[(size_t)(lane * 12 + k) * 4 + p];
#pragma unroll
    for (int off = 1; off < 64; off <<= 1) s += __shfl_xor(s, off, 64);
    if (lane == 0)
        out[p] = s * (1.0f / 18874368.0f) * weight[0] + bias_[0];
}

// ---------------------------------------------------------------------------
extern "C" void kernel_launch(void* const* d_in, const int* in_sizes, int n_in,
                              void* d_out, int out_size, void* d_ws, size_t ws_size,
                              hipStream_t stream) {
    const float* hid    = (const float*)d_in[0];
    const float* coords = (const float*)d_in[1];
    const float* W      = (const float*)d_in[2];
    const float* b_rbf  = (const float*)d_in[3];
    const float* weight = (const float*)d_in[4];
    const float* bias_  = (const float*)d_in[5];
    float* out = (float*)d_out;

    const size_t T_BYTES    = (size_t)NN * 2048 * sizeof(float);  // 6.29 MB
    const size_t HT_BYTES   = (size_t)DD * NN * sizeof(float);    // 196.6 KB
    const size_t PART_BYTES = (size_t)NN * 4 * sizeof(float);     // 12 KB
    const bool use_ws = ws_size >= T_BYTES + HT_BYTES + PART_BYTES + 64;

    float*    Tg       = (float*)d_ws;
    float*    hidT     = (float*)((char*)d_ws + T_BYTES);
    float*    partials = use_ws ? (float*)((char*)d_ws + T_BYTES + HT_BYTES) : (float*)d_ws;
    unsigned* ctr      = (unsigned*)((char*)d_ws + T_BYTES + HT_BYTES + PART_BYTES);

    if (use_ws) {
        k1_T<<<192, 256, 0, stream>>>(hid, W, Tg, hidT, ctr);
        k2_main<<<NN, 256, 0, stream>>>(hidT, coords, b_rbf, Tg, partials,
                                        ctr, weight, bias_, out);
    } else {
        k2_fb<<<NN, 256, 0, stream>>>(hid, coords, W, b_rbf, partials);
        k3_final<<<1, 256, 0, stream>>>(partials, weight, bias_, out);
    }
}

// Round 4
// 91.168 us; speedup vs baseline: 1.7551x; 1.7551x over previous
//
#include <hip/hip_runtime.h>
#include <hip/hip_bf16.h>
#include <math.h>

#define NN 768
#define DD 64
#define SS 32
#define PP 4

// mu = linspace(0,12,32) -> step 12/31 ; sigma = 12/32
#define MU_STEP   (12.0f / 31.0f)
#define INV2SIG2  3.55555555555f
// exp(-t^2*INV2SIG2) == exp2(t^2 * NEG2C)
#define NEG2C     (-INV2SIG2 * 1.4426950408889634f)

typedef __attribute__((ext_vector_type(8))) short bf16x8;
typedef __attribute__((ext_vector_type(4))) float f32x4;

__device__ __forceinline__ unsigned short f2bf(float f) {
    unsigned u = __float_as_uint(f);
    u += 0x7FFFu + ((u >> 16) & 1u);           // RNE
    return (unsigned short)(u >> 16);
}
__device__ __forceinline__ float bf2f(unsigned short b) {
    return __uint_as_float(((unsigned)b) << 16);
}

// ---------------------------------------------------------------------------
// Kernel 1 (grid=204):
//  blocks 0..191 : T[x][j*32+s] = sum_i hid[x][i]*W[i][j][s]  (fp32, to ws)
//  blocks 192..203: build A-fragments of hid in bf16 hi/lo planes:
//    element (y,j): t=y>>4, r=y&15, kh=j>>5, g=(j>>3)&3, e=j&7
//    hbX[ (t*1024) + kh*512 + (g*16+r)*8 + e ]
//  block 0 also zeroes the last-block counter.
// ---------------------------------------------------------------------------
__global__ __launch_bounds__(256) void k1_T(const float* __restrict__ hid,
                                            const float* __restrict__ W,
                                            float* __restrict__ T,
                                            unsigned short* __restrict__ hbHi,
                                            unsigned short* __restrict__ hbLo,
                                            unsigned* __restrict__ ctr) {
    const int b   = blockIdx.x;
    const int tid = threadIdx.x;
    if (b == 0 && tid == 0) *ctr = 0u;

    __shared__ float hs[16 * 64];

    if (b < 192) {
        const int cb  = b & 3;
        const int xb  = b >> 2;
        const int c0  = cb * 512;
        const int x0  = xb * 16;
        const int ct  = tid & 63;
        const int xt  = tid >> 6;

        {
            const float4 v = *reinterpret_cast<const float4*>(&hid[(size_t)x0 * 64 + tid * 4]);
            *reinterpret_cast<float4*>(&hs[tid * 4]) = v;
        }
        __syncthreads();

        float acc[4][8];
#pragma unroll
        for (int m = 0; m < 4; ++m)
#pragma unroll
            for (int u = 0; u < 8; ++u) acc[m][u] = 0.0f;

        const int cbase = c0 + ct * 8;
#pragma unroll 4
        for (int i = 0; i < 64; ++i) {
            const float4 w0 = *reinterpret_cast<const float4*>(&W[(size_t)i * 2048 + cbase]);
            const float4 w1 = *reinterpret_cast<const float4*>(&W[(size_t)i * 2048 + cbase + 4]);
#pragma unroll
            for (int m = 0; m < 4; ++m) {
                const float hm = hs[(xt * 4 + m) * 64 + i];
                acc[m][0] += hm * w0.x; acc[m][1] += hm * w0.y;
                acc[m][2] += hm * w0.z; acc[m][3] += hm * w0.w;
                acc[m][4] += hm * w1.x; acc[m][5] += hm * w1.y;
                acc[m][6] += hm * w1.z; acc[m][7] += hm * w1.w;
            }
        }

#pragma unroll
        for (int m = 0; m < 4; ++m) {
            const int x = x0 + xt * 4 + m;
            float4 o0, o1;
            o0.x = acc[m][0]; o0.y = acc[m][1]; o0.z = acc[m][2]; o0.w = acc[m][3];
            o1.x = acc[m][4]; o1.y = acc[m][5]; o1.z = acc[m][6]; o1.w = acc[m][7];
            *reinterpret_cast<float4*>(&T[(size_t)x * 2048 + cbase])     = o0;
            *reinterpret_cast<float4*>(&T[(size_t)x * 2048 + cbase + 4]) = o1;
        }
    } else {
        // fragment-ize hid: 12 blocks x 256 thr x 16 elems = 49152
        const int base = (b - 192) * 4096 + tid * 16;   // flat (y*64+j)
        const int y  = base >> 6;
        const int j0 = base & 63;
        const int t  = y >> 4;
        const int r  = y & 15;
        float hv[16];
#pragma unroll
        for (int c = 0; c < 4; ++c) {
            const float4 v = *reinterpret_cast<const float4*>(&hid[(size_t)y * 64 + j0 + c * 4]);
            hv[c * 4 + 0] = v.x; hv[c * 4 + 1] = v.y; hv[c * 4 + 2] = v.z; hv[c * 4 + 3] = v.w;
        }
#pragma unroll
        for (int n = 0; n < 16; ++n) {
            const int j  = j0 + n;
            const int kh = j >> 5;
            const int g  = (j >> 3) & 3;
            const int e  = j & 7;
            const int idx = t * 1024 + kh * 512 + (g * 16 + r) * 8 + e;
            const unsigned short hi = f2bf(hv[n]);
            const float lo = hv[n] - bf2f(hi);
            hbHi[idx] = hi;
            hbLo[idx] = f2bf(lo);
        }
    }
}

// ---------------------------------------------------------------------------
// Kernel 2 (grid=768, 256 thr = 4 waves): split-bf16 MFMA GEMM + rbf epilogue.
// Per block x:
//   prologue: dists d / NEG2C*d^2 for all (p,y) -> LDS; B-frags (T[x] hi/lo)
//             built in LDS then hoisted to VGPRs. ONE barrier total.
//   main: wave wv does y-tiles t = 4k+wv; per tile: 4 coalesced A-frag loads
//         (global, L2-resident), 12 MFMA, epilogue vs acc fragments
//         (C layout: col s = lane&15, row y = tile*16 + (lane>>4)*4 + reg).
//   reduction: wave butterfly + LDS + last-block-final (proven R2/R3).
// ---------------------------------------------------------------------------
__global__ __launch_bounds__(256, 4) void k2_main(const float* __restrict__ coords,
                                                  const float* __restrict__ b_rbf,
                                                  const float* __restrict__ Tg,
                                                  const unsigned short* __restrict__ hbHi,
                                                  const unsigned short* __restrict__ hbLo,
                                                  float* __restrict__ partials,
                                                  unsigned* __restrict__ ctr,
                                                  const float* __restrict__ weight,
                                                  const float* __restrict__ bias_,
                                                  float* __restrict__ out) {
    const int x   = blockIdx.x;
    const int tid = threadIdx.x;
    const int l   = tid & 63;
    const int wv  = tid >> 6;
    const int g   = l >> 4;        // k-subgroup / row-subgroup
    const int c16 = l & 15;        // col (s within tile)

    __shared__ float d_s[PP][NN];          // 12 KB  distances
    __shared__ float c_s[PP][NN];          // 12 KB  NEG2C*d^2
    __shared__ unsigned short bh_s[2048];  // 4 KB   B-frag hi
    __shared__ unsigned short bl_s[2048];  // 4 KB   B-frag lo
    __shared__ float red16[16];
    __shared__ unsigned flagS;

    // ---- dist pass: 12 iterations cover 4p x 768y ----
#pragma unroll
    for (int p = 0; p < PP; ++p) {
        const float cxx = coords[((size_t)p * NN + x) * 3 + 0];
        const float cxy = coords[((size_t)p * NN + x) * 3 + 1];
        const float cxz = coords[((size_t)p * NN + x) * 3 + 2];
#pragma unroll
        for (int yb = 0; yb < 3; ++yb) {
            const int y = yb * 256 + tid;
            const float dx = cxx - coords[((size_t)p * NN + y) * 3 + 0];
            const float dy = cxy - coords[((size_t)p * NN + y) * 3 + 1];
            const float dz = cxz - coords[((size_t)p * NN + y) * 3 + 2];
            const float d2 = fmaf(dx, dx, fmaf(dy, dy, fmaf(dz, dz, 1e-12f)));
            d_s[p][y] = sqrtf(d2);
            c_s[p][y] = d2 * NEG2C;
        }
    }

    // ---- B-frag build: thread tid == frag slot (st=tid>>7, kh=(tid>>6)&1, fl=tid&63) ----
    {
        const int st = tid >> 7;
        const int kh = (tid >> 6) & 1;
        const int fl = tid & 63;
        const int jb = kh * 32 + (fl >> 4) * 8;
        const int s  = st * 16 + (fl & 15);
#pragma unroll
        for (int e = 0; e < 8; ++e) {
            const float tv = Tg[(size_t)x * 2048 + (size_t)(jb + e) * 32 + s];
            const unsigned short hi = f2bf(tv);
            const float lo = tv - bf2f(hi);
            bh_s[tid * 8 + e] = hi;
            bl_s[tid * 8 + e] = f2bf(lo);
        }
    }
    __syncthreads();   // the only barrier before reduction

    // ---- hoist B-frags to registers (8 x ds_read_b128) ----
    const bf16x8 bH00 = *reinterpret_cast<const bf16x8*>(&bh_s[(0 * 64 + l) * 8]);
    const bf16x8 bH01 = *reinterpret_cast<const bf16x8*>(&bh_s[(1 * 64 + l) * 8]);
    const bf16x8 bH10 = *reinterpret_cast<const bf16x8*>(&bh_s[(2 * 64 + l) * 8]);
    const bf16x8 bH11 = *reinterpret_cast<const bf16x8*>(&bh_s[(3 * 64 + l) * 8]);
    const bf16x8 bL00 = *reinterpret_cast<const bf16x8*>(&bl_s[(0 * 64 + l) * 8]);
    const bf16x8 bL01 = *reinterpret_cast<const bf16x8*>(&bl_s[(1 * 64 + l) * 8]);
    const bf16x8 bL10 = *reinterpret_cast<const bf16x8*>(&bl_s[(2 * 64 + l) * 8]);
    const bf16x8 bL11 = *reinterpret_cast<const bf16x8*>(&bl_s[(3 * 64 + l) * 8]);

    // per-lane rbf constants for s0 = c16, s1 = 16+c16
    const float mu0 = (float)(c16)      * MU_STEP;
    const float mu1 = (float)(16 + c16) * MU_STEP;
    const float A0 = -2.0f * NEG2C * mu0, B0 = NEG2C * mu0 * mu0;
    const float A1 = -2.0f * NEG2C * mu1, B1 = NEG2C * mu1 * mu1;
    const float brbf0 = b_rbf[c16];
    const float brbf1 = b_rbf[16 + c16];

    float eA[PP] = {0, 0, 0, 0};
    float eB[PP] = {0, 0, 0, 0};

    for (int k = 0; k < 12; ++k) {
        const int t  = (k << 2) + wv;          // y-tile index 0..47
        const int ab = t * 1024 + l * 8;       // A-frag base (kh stride 512)

        const bf16x8 aH0 = *reinterpret_cast<const bf16x8*>(&hbHi[ab]);
        const bf16x8 aH1 = *reinterpret_cast<const bf16x8*>(&hbHi[ab + 512]);
        const bf16x8 aL0 = *reinterpret_cast<const bf16x8*>(&hbLo[ab]);
        const bf16x8 aL1 = *reinterpret_cast<const bf16x8*>(&hbLo[ab + 512]);

        f32x4 acc0 = {0.0f, 0.0f, 0.0f, 0.0f};
        f32x4 acc1 = {0.0f, 0.0f, 0.0f, 0.0f};
        acc0 = __builtin_amdgcn_mfma_f32_16x16x32_bf16(aH0, bH00, acc0, 0, 0, 0);
        acc1 = __builtin_amdgcn_mfma_f32_16x16x32_bf16(aH0, bH10, acc1, 0, 0, 0);
        acc0 = __builtin_amdgcn_mfma_f32_16x16x32_bf16(aH1, bH01, acc0, 0, 0, 0);
        acc1 = __builtin_amdgcn_mfma_f32_16x16x32_bf16(aH1, bH11, acc1, 0, 0, 0);
        acc0 = __builtin_amdgcn_mfma_f32_16x16x32_bf16(aH0, bL00, acc0, 0, 0, 0);
        acc1 = __builtin_amdgcn_mfma_f32_16x16x32_bf16(aH0, bL10, acc1, 0, 0, 0);
        acc0 = __builtin_amdgcn_mfma_f32_16x16x32_bf16(aH1, bL01, acc0, 0, 0, 0);
        acc1 = __builtin_amdgcn_mfma_f32_16x16x32_bf16(aH1, bL11, acc1, 0, 0, 0);
        acc0 = __builtin_amdgcn_mfma_f32_16x16x32_bf16(aL0, bH00, acc0, 0, 0, 0);
        acc1 = __builtin_amdgcn_mfma_f32_16x16x32_bf16(aL0, bH10, acc1, 0, 0, 0);
        acc0 = __builtin_amdgcn_mfma_f32_16x16x32_bf16(aL1, bH01, acc0, 0, 0, 0);
        acc1 = __builtin_amdgcn_mfma_f32_16x16x32_bf16(aL1, bH11, acc1, 0, 0, 0);

        // epilogue: lane holds C rows yb..yb+3, cols s0 (acc0) and s1 (acc1)
        const int yb = t * 16 + g * 4;
        const float ab00 = acc0[0] + brbf0, ab01 = acc0[1] + brbf0,
                    ab02 = acc0[2] + brbf0, ab03 = acc0[3] + brbf0;
        const float ab10 = acc1[0] + brbf1, ab11 = acc1[1] + brbf1,
                    ab12 = acc1[2] + brbf1, ab13 = acc1[3] + brbf1;

#pragma unroll
        for (int p = 0; p < PP; ++p) {
            const f32x4 dd = *reinterpret_cast<const f32x4*>(&d_s[p][yb]);
            const f32x4 cc = *reinterpret_cast<const f32x4*>(&c_s[p][yb]);
#pragma unroll
            for (int r = 0; r < 4; ++r) {
                if (yb + r == x) continue;     // diagonal mask
                const float d  = dd[r];
                const float c0v = cc[r] + B0;
                const float c1v = cc[r] + B1;
                const float w0 = __builtin_exp2f(fmaf(A0, d, c0v));
                const float w1 = __builtin_exp2f(fmaf(A1, d, c1v));
                const float a0 = (r == 0) ? ab00 : (r == 1) ? ab01 : (r == 2) ? ab02 : ab03;
                const float a1 = (r == 0) ? ab10 : (r == 1) ? ab11 : (r == 2) ? ab12 : ab13;
                eA[p] = fmaf(a0, w0, eA[p]);
                eB[p] = fmaf(a1, w1, eB[p]);
            }
        }
    }

    // ---- deterministic reduction ----
    float e[PP];
#pragma unroll
    for (int p = 0; p < PP; ++p) e[p] = eA[p] + eB[p];
#pragma unroll
    for (int off = 1; off < 64; off <<= 1)
#pragma unroll
        for (int p = 0; p < PP; ++p) e[p] += __shfl_xor(e[p], off, 64);

    if (l == 0) {
#pragma unroll
        for (int p = 0; p < PP; ++p) red16[wv * 4 + p] = e[p];
    }
    __syncthreads();
    if (tid < 4) {
        const float s = red16[0 * 4 + tid] + red16[1 * 4 + tid] +
                        red16[2 * 4 + tid] + red16[3 * 4 + tid];
        partials[(size_t)x * 4 + tid] = s;
    }

    // ---- fused final reduction: last block sums all partials ----
    __threadfence();
    __syncthreads();
    if (tid == 0) {
        const unsigned old = atomicAdd(ctr, 1u);
        flagS = (old == NN - 1) ? 1u : 0u;
    }
    __syncthreads();
    if (flagS) {
        __threadfence();
        const int p    = tid >> 6;
        const int lane = tid & 63;
        float s = 0.0f;
#pragma unroll
        for (int kk = 0; kk < 12; ++kk)
            s += partials[(size_t)(lane * 12 + kk) * 4 + p];
#pragma unroll
        for (int off = 1; off < 64; off <<= 1) s += __shfl_xor(s, off, 64);
        if (lane == 0)
            out[p] = s * (1.0f / 18874368.0f) * weight[0] + bias_[0];
    }
}

// ---------------------------------------------------------------------------
// Fallback path (ws too small): self-contained fp32 kernel + final reduce
// ---------------------------------------------------------------------------
__global__ __launch_bounds__(256, 4) void k2_fb(const float* __restrict__ hid,
                                                const float* __restrict__ coords,
                                                const float* __restrict__ W,
                                                const float* __restrict__ b_rbf,
                                                float* __restrict__ partials) {
    const int x   = blockIdx.x;
    const int tid = threadIdx.x;
    const int ty  = tid & 63;
    const int ts  = tid >> 6;

    __shared__ float pool[2048 + 64 * 128];
    float* T_l = pool;
    float* h_t = pool + 2048;

    {
        float a0[4] = {0, 0, 0, 0}, a1[4] = {0, 0, 0, 0};
        for (int i = 0; i < 64; ++i) {
            const float hv = hid[(size_t)x * 64 + i];
            const float4 w0 = *reinterpret_cast<const float4*>(&W[(size_t)i * 2048 + tid * 4]);
            const float4 w1 = *reinterpret_cast<const float4*>(&W[(size_t)i * 2048 + 1024 + tid * 4]);
            a0[0] += hv * w0.x; a0[1] += hv * w0.y; a0[2] += hv * w0.z; a0[3] += hv * w0.w;
            a1[0] += hv * w1.x; a1[1] += hv * w1.y; a1[2] += hv * w1.z; a1[3] += hv * w1.w;
        }
        T_l[tid * 4 + 0] = a0[0]; T_l[tid * 4 + 1] = a0[1];
        T_l[tid * 4 + 2] = a0[2]; T_l[tid * 4 + 3] = a0[3];
        T_l[1024 + tid * 4 + 0] = a1[0]; T_l[1024 + tid * 4 + 1] = a1[1];
        T_l[1024 + tid * 4 + 2] = a1[2]; T_l[1024 + tid * 4 + 3] = a1[3];
    }

    float mu_reg[8], b_reg[8];
#pragma unroll
    for (int u = 0; u < 8; ++u) {
        const int s = ts * 8 + u;
        mu_reg[u] = (float)s * MU_STEP;
        b_reg[u]  = b_rbf[s];
    }
    float cx[PP][3];
#pragma unroll
    for (int p = 0; p < PP; ++p)
#pragma unroll
        for (int c = 0; c < 3; ++c)
            cx[p][c] = coords[(size_t)p * NN * 3 + (size_t)x * 3 + c];

    float e[PP] = {0.0f, 0.0f, 0.0f, 0.0f};
    const int srow = tid >> 1;
    const int r0   = (tid & 1) * 8;
    const int hoff = ty * 2;
    const int toff = ts * 8;

    for (int ch = 0; ch < 6; ++ch) {
        const int y0 = ch * 128;
        __syncthreads();
        {
            const int y = y0 + srow;
#pragma unroll
            for (int r = 0; r < 8; ++r) {
                const float4 v = *reinterpret_cast<const float4*>(
                    &hid[(size_t)y * 64 + (r0 + r) * 4]);
                const int j = (r0 + r) * 4;
                h_t[(j + 0) * 128 + srow] = v.x;
                h_t[(j + 1) * 128 + srow] = v.y;
                h_t[(j + 2) * 128 + srow] = v.z;
                h_t[(j + 3) * 128 + srow] = v.w;
            }
        }
        __syncthreads();

        float acc[2][8];
#pragma unroll
        for (int i = 0; i < 2; ++i)
#pragma unroll
            for (int u = 0; u < 8; ++u) acc[i][u] = 0.0f;

#pragma unroll 4
        for (int j = 0; j < 64; ++j) {
            const float h0 = h_t[j * 128 + hoff];
            const float h1 = h_t[j * 128 + hoff + 1];
            const float4 t0 = *reinterpret_cast<const float4*>(&T_l[j * 32 + toff]);
            const float4 t1 = *reinterpret_cast<const float4*>(&T_l[j * 32 + toff + 4]);
            acc[0][0] += h0 * t0.x; acc[0][1] += h0 * t0.y; acc[0][2] += h0 * t0.z; acc[0][3] += h0 * t0.w;
            acc[0][4] += h0 * t1.x; acc[0][5] += h0 * t1.y; acc[0][6] += h0 * t1.z; acc[0][7] += h0 * t1.w;
            acc[1][0] += h1 * t0.x; acc[1][1] += h1 * t0.y; acc[1][2] += h1 * t0.z; acc[1][3] += h1 * t0.w;
            acc[1][4] += h1 * t1.x; acc[1][5] += h1 * t1.y; acc[1][6] += h1 * t1.z; acc[1][7] += h1 * t1.w;
        }

        float ab[2][8];
#pragma unroll
        for (int i = 0; i < 2; ++i)
#pragma unroll
            for (int u = 0; u < 8; ++u) ab[i][u] = acc[i][u] + b_reg[u];

#pragma unroll
        for (int i = 0; i < 2; ++i) {
            const int y = y0 + hoff + i;
            if (y == x) continue;
#pragma unroll
            for (int p = 0; p < PP; ++p) {
                const float dx = cx[p][0] - coords[(size_t)p * NN * 3 + (size_t)y * 3 + 0];
                const float dy = cx[p][1] - coords[(size_t)p * NN * 3 + (size_t)y * 3 + 1];
                const float dz = cx[p][2] - coords[(size_t)p * NN * 3 + (size_t)y * 3 + 2];
                const float d  = sqrtf(dx * dx + dy * dy + dz * dz + 1e-12f);
                float ep = 0.0f;
#pragma unroll
                for (int u = 0; u < 8; ++u) {
                    const float t = d - mu_reg[u];
                    const float w = __builtin_exp2f(t * t * NEG2C);
                    ep = fmaf(ab[i][u], w, ep);
                }
                e[p] += ep;
            }
        }
    }

#pragma unroll
    for (int off = 1; off < 64; off <<= 1)
#pragma unroll
        for (int p = 0; p < PP; ++p) e[p] += __shfl_xor(e[p], off, 64);

    __syncthreads();
    if (ty == 0) {
#pragma unroll
        for (int p = 0; p < PP; ++p) pool[ts * 4 + p] = e[p];
    }
    __syncthreads();
    if (tid < 4) {
        const float s = pool[0 * 4 + tid] + pool[1 * 4 + tid] +
                        pool[2 * 4 + tid] + pool[3 * 4 + tid];
        partials[(size_t)x * 4 + tid] = s;
    }
}

__global__ __launch_bounds__(256) void k3_final(const float* __restrict__ partials,
                                                const float* __restrict__ weight,
                                                const float* __restrict__ bias_,
                                                float* __restrict__ out) {
    const int p    = threadIdx.x >> 6;
    const int lane = threadIdx.x & 63;
    float s = 0.0f;
#pragma unroll
    for (int k = 0; k < 12; ++k) s += partials[(size_t)(lane * 12 + k) * 4 + p];
#pragma unroll
    for (int off = 1; off < 64; off <<= 1) s += __shfl_xor(s, off, 64);
    if (lane == 0)
        out[p] = s * (1.0f / 18874368.0f) * weight[0] + bias_[0];
}

// ---------------------------------------------------------------------------
extern "C" void kernel_launch(void* const* d_in, const int* in_sizes, int n_in,
                              void* d_out, int out_size, void* d_ws, size_t ws_size,
                              hipStream_t stream) {
    const float* hid    = (const float*)d_in[0];
    const float* coords = (const float*)d_in[1];
    const float* W      = (const float*)d_in[2];
    const float* b_rbf  = (const float*)d_in[3];
    const float* weight = (const float*)d_in[4];
    const float* bias_  = (const float*)d_in[5];
    float* out = (float*)d_out;

    const size_t T_BYTES    = (size_t)NN * 2048 * sizeof(float);        // 6.29 MB
    const size_t HB_BYTES   = (size_t)48 * 1024 * sizeof(unsigned short); // 96 KB/plane
    const size_t PART_BYTES = (size_t)NN * 4 * sizeof(float);           // 12 KB
    const bool use_ws = ws_size >= T_BYTES + 2 * HB_BYTES + PART_BYTES + 64;

    float*          Tg       = (float*)d_ws;
    unsigned short* hbHi     = (unsigned short*)((char*)d_ws + T_BYTES);
    unsigned short* hbLo     = (unsigned short*)((char*)d_ws + T_BYTES + HB_BYTES);
    float*          partials = use_ws ? (float*)((char*)d_ws + T_BYTES + 2 * HB_BYTES)
                                      : (float*)d_ws;
    unsigned*       ctr      = (unsigned*)((char*)d_ws + T_BYTES + 2 * HB_BYTES + PART_BYTES);

    if (use_ws) {
        k1_T<<<204, 256, 0, stream>>>(hid, W, Tg, hbHi, hbLo, ctr);
        k2_main<<<NN, 256, 0, stream>>>(coords, b_rbf, Tg, hbHi, hbLo, partials,
                                        ctr, weight, bias_, out);
    } else {
        k2_fb<<<NN, 256, 0, stream>>>(hid, coords, W, b_rbf, partials);
        k3_final<<<1, 256, 0, stream>>>(partials, weight, bias_, out);
    }
}